// Round 1
// baseline (855.664 us; speedup 1.0000x reference)
//
#include <hip/hip_runtime.h>

#define NSIG   32768
#define NATOM  512
#define MDIM   64
#define SPARSITY 5
#define EPS    1e-10

// ---------------- prep: normalize dictionary into fp64, compute atom norms ----
__global__ __launch_bounds__(256) void prep_kernel(const float* __restrict__ D,
                                                   double* __restrict__ Dd,
                                                   double* __restrict__ nrm2,
                                                   double* __restrict__ loss_acc) {
  int n = blockIdx.x * blockDim.x + threadIdx.x;
  if (n == 0) loss_acc[0] = 0.0;
  if (n >= NATOM) return;
  double ss = 0.0;
  for (int c = 0; c < MDIM; ++c) {
    double v = (double)D[c * NATOM + n];
    ss += v * v;
  }
  double norm = sqrt(ss);
  if (norm < 1e-10) norm = 1e-10;
  double s2 = 0.0;
  for (int c = 0; c < MDIM; ++c) {
    double v = (double)D[c * NATOM + n] / norm;
    Dd[(size_t)n * MDIM + c] = v;
    s2 += v * v;
  }
  nrm2[n] = s2;
}

// ---------------- main OMP kernel -------------------------------------------
// block = 512 threads = 8 waves; lane = signal (64 signals/block), wave w owns
// atoms [64w, 64w+64). Residual r replicated per wave in fp64 registers.
__global__ __launch_bounds__(512) void omp_kernel(const float* __restrict__ z_e,
                                                  const double* __restrict__ Dd,
                                                  const double* __restrict__ nrm2,
                                                  float* __restrict__ z_dl,
                                                  float* __restrict__ coeff,
                                                  double* __restrict__ loss_acc) {
  __shared__ double s_best[8][64];
  __shared__ double s_corr[8][64];
  __shared__ int    s_idx[8][64];

  const int lane = threadIdx.x & 63;
  const int w = __builtin_amdgcn_readfirstlane(threadIdx.x >> 6); // uniform wave id
  const int t = blockIdx.x * 64 + lane;   // signal index
  const int b = t & 31;
  const int l = t >> 5;
  const float* xp = z_e + (size_t)b * (MDIM * 1024) + l;   // + c*1024

  double r[MDIM];
#pragma unroll
  for (int c = 0; c < MDIM; ++c) r[c] = (double)xp[(size_t)c * 1024];

  unsigned long long mw = ~0ull;   // availability mask for this wave's 64 atoms
  const int nbase = w * 64;

  for (int it = 0; it < SPARSITY; ++it) {
    double best = -1.0, bcorr = 0.0;
    int bidx = nbase;
#pragma unroll 2
    for (int k = 0; k < 64; ++k) {
      const double* dp = Dd + ((size_t)(nbase + k) << 6);  // uniform -> s_load
      double a0=0,a1=0,a2=0,a3=0,a4=0,a5=0,a6=0,a7=0;
#pragma unroll
      for (int c = 0; c < MDIM; c += 8) {
        a0 += dp[c+0]*r[c+0]; a1 += dp[c+1]*r[c+1];
        a2 += dp[c+2]*r[c+2]; a3 += dp[c+3]*r[c+3];
        a4 += dp[c+4]*r[c+4]; a5 += dp[c+5]*r[c+5];
        a6 += dp[c+6]*r[c+6]; a7 += dp[c+7]*r[c+7];
      }
      double corr = ((a0+a1)+(a2+a3))+((a4+a5)+(a6+a7));
      double aa = fabs(corr);
      bool avail = (mw >> k) & 1ull;
      bool better = avail && (aa > best);
      best  = better ? aa : best;
      bcorr = better ? corr : bcorr;
      bidx  = better ? (nbase + k) : bidx;
    }
    s_best[w][lane] = best;
    s_corr[w][lane] = bcorr;
    s_idx[w][lane]  = bidx;
    __syncthreads();
    // every wave computes the global winner identically (ascending w => first-max)
    double gbest = -2.0, gcorr = 0.0;
    int gidx = 0;
#pragma unroll
    for (int w2 = 0; w2 < 8; ++w2) {
      double cb = s_best[w2][lane];
      double cc = s_corr[w2][lane];
      int    ci = s_idx[w2][lane];
      bool better = cb > gbest;
      gbest = better ? cb : gbest;
      gcorr = better ? cc : gcorr;
      gidx  = better ? ci : gidx;
    }
    __syncthreads();   // LDS consumed; safe to overwrite next iteration

    double alpha = gcorr / (nrm2[gidx] + EPS);
    if ((gidx >> 6) == w) mw &= ~(1ull << (gidx & 63));
    if (w == 0) coeff[(size_t)gidx * NSIG + t] = (float)alpha;

    const double* dsel = Dd + ((size_t)gidx << 6);  // divergent -> vector loads
#pragma unroll
    for (int c = 0; c < MDIM; ++c) r[c] -= alpha * dsel[c];
  }

  if (w == 0) {
    double s2 = 0.0;
#pragma unroll
    for (int c = 0; c < MDIM; ++c) {
      double x = (double)xp[(size_t)c * 1024];
      float zv = (float)(x - r[c]);
      z_dl[(size_t)(b * MDIM + c) * 1024 + l] = zv;
      double diff = (double)zv - x;
      s2 += diff * diff;
    }
    for (int o = 32; o > 0; o >>= 1) s2 += __shfl_down(s2, o);
    if (lane == 0) atomicAdd(loss_acc, s2);
  }
}

// ---------------- finalize loss ---------------------------------------------
__global__ void finalize_kernel(const double* __restrict__ loss_acc,
                                float* __restrict__ loss_out) {
  loss_out[0] = (float)(1.25 * loss_acc[0] / 2097152.0);
}

extern "C" void kernel_launch(void* const* d_in, const int* in_sizes, int n_in,
                              void* d_out, int out_size, void* d_ws, size_t ws_size,
                              hipStream_t stream) {
  const float* z_e = (const float*)d_in[0];
  const float* D   = (const float*)d_in[1];

  float* out      = (float*)d_out;
  float* z_dl     = out;                       // 2097152 elems
  float* loss_out = out + 2097152;             // 1 elem
  float* coeff    = out + 2097153;             // 512*32768 elems

  char*   ws       = (char*)d_ws;
  double* loss_acc = (double*)ws;                              // 8 B
  double* Dd       = (double*)(ws + 4096);                     // 512*64*8 = 256 KiB
  double* nrm2     = (double*)(ws + 4096 + (size_t)NATOM * MDIM * 8); // 4 KiB

  // zero the coefficients region (harness poisons d_out; z_dl/loss are fully
  // rewritten by kernels below)
  hipMemsetAsync(coeff, 0, (size_t)NATOM * NSIG * sizeof(float), stream);

  prep_kernel<<<2, 256, 0, stream>>>(D, Dd, nrm2, loss_acc);
  omp_kernel<<<NSIG / 64, 512, 0, stream>>>(z_e, Dd, nrm2, z_dl, coeff, loss_acc);
  finalize_kernel<<<1, 1, 0, stream>>>(loss_acc, loss_out);
}

// Round 2
// 582.784 us; speedup vs baseline: 1.4682x; 1.4682x over previous
//
#include <hip/hip_runtime.h>
#include <stdint.h>

#define NSIG   32768
#define NATOM  512
#define MDIM   64
#define SPAR   5
#define EPS    1e-10

// Force a pointer into VGPRs so subsequent loads become global_load_* (vmcnt
// pipelined) instead of s_load_* (48-SGPR budget serializes on lgkmcnt).
__device__ __forceinline__ const double* vload_ptr(const double* p) {
  uint64_t u = (uint64_t)p;
  asm("" : "+v"(u));
  return (const double*)u;
}

// ---------------- prep: normalize dictionary into fp64, compute atom norms ----
__global__ __launch_bounds__(256) void prep_kernel(const float* __restrict__ D,
                                                   double* __restrict__ Dd,
                                                   double* __restrict__ nrm2,
                                                   double* __restrict__ loss_acc) {
  int n = blockIdx.x * blockDim.x + threadIdx.x;
  if (n == 0) loss_acc[0] = 0.0;
  if (n >= NATOM) return;
  double ss = 0.0;
  for (int c = 0; c < MDIM; ++c) {
    double v = (double)D[c * NATOM + n];
    ss += v * v;
  }
  double norm = sqrt(ss);
  if (norm < 1e-10) norm = 1e-10;
  double s2 = 0.0;
  for (int c = 0; c < MDIM; ++c) {
    double v = (double)D[c * NATOM + n] / norm;
    Dd[(size_t)n * MDIM + c] = v;
    s2 += v * v;
  }
  nrm2[n] = s2;
}

// ---------------- Gram matrix G = Dn^T Dn (fp64, 512x512) --------------------
__global__ __launch_bounds__(512) void gram_kernel(const double* __restrict__ Dd,
                                                   double* __restrict__ G) {
  int i = blockIdx.x;       // row atom
  int j = threadIdx.x;      // col atom
  const double* di = Dd + ((size_t)i << 6);
  const double* dj = vload_ptr(Dd + ((size_t)j << 6));
  double s = 0.0;
#pragma unroll
  for (int c = 0; c < MDIM; ++c) s += di[c] * dj[c];
  G[(size_t)i * NATOM + j] = s;
}

// ---------------- main OMP kernel (Gram recursion) ---------------------------
// block = 512 threads = 8 waves; lane = signal (64 signals/block), wave w owns
// atoms [64w, 64w+64). corr kept in 64 fp64 registers per lane; after the
// initial D^T x, iterations update corr via G instead of rescanning D.
__global__ __launch_bounds__(512) void omp2_kernel(const float* __restrict__ z_e,
                                                   const double* __restrict__ Dd,
                                                   const double* __restrict__ nrm2,
                                                   const double* __restrict__ G,
                                                   float* __restrict__ z_dl,
                                                   float* __restrict__ coeff,
                                                   double* __restrict__ loss_acc) {
  __shared__ double xs[MDIM][64];     // x fp64, [dim][lane]  (32 KiB)
  __shared__ double s_best[8][64];
  __shared__ double s_corr[8][64];
  __shared__ int    s_idx[8][64];

  const int lane = threadIdx.x & 63;
  const int w = __builtin_amdgcn_readfirstlane(threadIdx.x >> 6);
  const int t = blockIdx.x * 64 + lane;   // signal index
  const int b = t & 31;
  const int l = t >> 5;
  const float* xp = z_e + (size_t)b * (MDIM * 1024) + l;

  // stage x into LDS: wave w loads dims [8w, 8w+8) for its 64 lanes
#pragma unroll
  for (int j = 0; j < 8; ++j) {
    int c = w * 8 + j;
    xs[c][lane] = (double)xp[(size_t)c * 1024];
  }
  __syncthreads();

  const int nbase = w * 64;
  double cor[64];
#pragma unroll
  for (int k = 0; k < 64; ++k) cor[k] = 0.0;

  // phase 1: cor[k] = <D[nbase+k], x>   (dim chunks rolled, k fully unrolled
  // so cor[] stays in registers; D loads forced to vector path)
  for (int cd = 0; cd < MDIM; cd += 8) {
    double x8[8];
#pragma unroll
    for (int j = 0; j < 8; ++j) x8[j] = xs[cd + j][lane];
#pragma unroll
    for (int k = 0; k < 64; ++k) {
      const double* dp = vload_ptr(Dd + (((size_t)(nbase + k)) << 6) + cd);
      cor[k] += dp[0]*x8[0] + dp[1]*x8[1] + dp[2]*x8[2] + dp[3]*x8[3]
              + dp[4]*x8[4] + dp[5]*x8[5] + dp[6]*x8[6] + dp[7]*x8[7];
    }
  }

  unsigned long long mw = ~0ull;   // availability of this wave's 64 atoms
  int sel[SPAR];
  double al[SPAR];

  for (int it = 0; it < SPAR; ++it) {
    // local argmax over this wave's atoms (first-max-wins, ascending k)
    double best = -1.0, bcorr = 0.0;
    int bidx = nbase;
#pragma unroll
    for (int k = 0; k < 64; ++k) {
      double aa = fabs(cor[k]);
      bool avail = (mw >> k) & 1ull;
      bool better = avail && (aa > best);
      best  = better ? aa : best;
      bcorr = better ? cor[k] : bcorr;
      bidx  = better ? (nbase + k) : bidx;
    }
    s_best[w][lane] = best;
    s_corr[w][lane] = bcorr;
    s_idx[w][lane]  = bidx;
    __syncthreads();
    // global winner, identical in every wave (ascending w => first-max)
    double gbest = -2.0, gcorr = 0.0;
    int gidx = 0;
#pragma unroll
    for (int w2 = 0; w2 < 8; ++w2) {
      double cb = s_best[w2][lane];
      double cc = s_corr[w2][lane];
      int    ci = s_idx[w2][lane];
      bool better = cb > gbest;
      gbest = better ? cb : gbest;
      gcorr = better ? cc : gcorr;
      gidx  = better ? ci : gidx;
    }
    __syncthreads();

    double alpha = gcorr / (nrm2[gidx] + EPS);
    if ((gidx >> 6) == w) mw &= ~(1ull << (gidx & 63));
    if (w == 0) coeff[(size_t)gidx * NSIG + t] = (float)alpha;
    sel[it] = gidx;
    al[it]  = alpha;

    if (it != SPAR - 1) {
      // exact identity: corr_{t+1} = corr_t - alpha * G[:, gidx]
      const double* gp = vload_ptr(G + (size_t)gidx * NATOM + nbase);
#pragma unroll
      for (int k = 0; k < 64; ++k) cor[k] -= alpha * gp[k];
    }
  }

  // epilogue (wave 0): z_dl = sum_t al[t] * d_{sel[t]};  loss = sum (zv - x)^2
  if (w == 0) {
    double s2 = 0.0;
    for (int c = 0; c < MDIM; ++c) {
      double v = al[0] * Dd[(((size_t)sel[0]) << 6) + c];
#pragma unroll
      for (int tt = 1; tt < SPAR; ++tt)
        v += al[tt] * Dd[(((size_t)sel[tt]) << 6) + c];
      float zv = (float)v;
      z_dl[(size_t)(b * MDIM + c) * 1024 + l] = zv;
      double diff = (double)zv - xs[c][lane];
      s2 += diff * diff;
    }
    for (int o = 32; o > 0; o >>= 1) s2 += __shfl_down(s2, o);
    if (lane == 0) atomicAdd(loss_acc, s2);
  }
}

// ---------------- fallback: direct recompute (round-1 kernel) ----------------
__global__ __launch_bounds__(512) void omp_direct_kernel(const float* __restrict__ z_e,
                                                         const double* __restrict__ Dd,
                                                         const double* __restrict__ nrm2,
                                                         float* __restrict__ z_dl,
                                                         float* __restrict__ coeff,
                                                         double* __restrict__ loss_acc) {
  __shared__ double s_best[8][64];
  __shared__ double s_corr[8][64];
  __shared__ int    s_idx[8][64];

  const int lane = threadIdx.x & 63;
  const int w = __builtin_amdgcn_readfirstlane(threadIdx.x >> 6);
  const int t = blockIdx.x * 64 + lane;
  const int b = t & 31;
  const int l = t >> 5;
  const float* xp = z_e + (size_t)b * (MDIM * 1024) + l;

  double r[MDIM];
#pragma unroll
  for (int c = 0; c < MDIM; ++c) r[c] = (double)xp[(size_t)c * 1024];

  unsigned long long mw = ~0ull;
  const int nbase = w * 64;

  for (int it = 0; it < SPAR; ++it) {
    double best = -1.0, bcorr = 0.0;
    int bidx = nbase;
#pragma unroll 2
    for (int k = 0; k < 64; ++k) {
      const double* dp = vload_ptr(Dd + ((size_t)(nbase + k) << 6));
      double a0=0,a1=0,a2=0,a3=0,a4=0,a5=0,a6=0,a7=0;
#pragma unroll
      for (int c = 0; c < MDIM; c += 8) {
        a0 += dp[c+0]*r[c+0]; a1 += dp[c+1]*r[c+1];
        a2 += dp[c+2]*r[c+2]; a3 += dp[c+3]*r[c+3];
        a4 += dp[c+4]*r[c+4]; a5 += dp[c+5]*r[c+5];
        a6 += dp[c+6]*r[c+6]; a7 += dp[c+7]*r[c+7];
      }
      double corr = ((a0+a1)+(a2+a3))+((a4+a5)+(a6+a7));
      double aa = fabs(corr);
      bool avail = (mw >> k) & 1ull;
      bool better = avail && (aa > best);
      best  = better ? aa : best;
      bcorr = better ? corr : bcorr;
      bidx  = better ? (nbase + k) : bidx;
    }
    s_best[w][lane] = best;
    s_corr[w][lane] = bcorr;
    s_idx[w][lane]  = bidx;
    __syncthreads();
    double gbest = -2.0, gcorr = 0.0;
    int gidx = 0;
#pragma unroll
    for (int w2 = 0; w2 < 8; ++w2) {
      double cb = s_best[w2][lane];
      double cc = s_corr[w2][lane];
      int    ci = s_idx[w2][lane];
      bool better = cb > gbest;
      gbest = better ? cb : gbest;
      gcorr = better ? cc : gcorr;
      gidx  = better ? ci : gidx;
    }
    __syncthreads();

    double alpha = gcorr / (nrm2[gidx] + EPS);
    if ((gidx >> 6) == w) mw &= ~(1ull << (gidx & 63));
    if (w == 0) coeff[(size_t)gidx * NSIG + t] = (float)alpha;

    const double* dsel = Dd + ((size_t)gidx << 6);
#pragma unroll
    for (int c = 0; c < MDIM; ++c) r[c] -= alpha * dsel[c];
  }

  if (w == 0) {
    double s2 = 0.0;
#pragma unroll
    for (int c = 0; c < MDIM; ++c) {
      double x = (double)xp[(size_t)c * 1024];
      float zv = (float)(x - r[c]);
      z_dl[(size_t)(b * MDIM + c) * 1024 + l] = zv;
      double diff = (double)zv - x;
      s2 += diff * diff;
    }
    for (int o = 32; o > 0; o >>= 1) s2 += __shfl_down(s2, o);
    if (lane == 0) atomicAdd(loss_acc, s2);
  }
}

// ---------------- finalize loss ---------------------------------------------
__global__ void finalize_kernel(const double* __restrict__ loss_acc,
                                float* __restrict__ loss_out) {
  loss_out[0] = (float)(1.25 * loss_acc[0] / 2097152.0);
}

extern "C" void kernel_launch(void* const* d_in, const int* in_sizes, int n_in,
                              void* d_out, int out_size, void* d_ws, size_t ws_size,
                              hipStream_t stream) {
  const float* z_e = (const float*)d_in[0];
  const float* D   = (const float*)d_in[1];

  float* out      = (float*)d_out;
  float* z_dl     = out;                       // 2097152 elems
  float* loss_out = out + 2097152;             // 1 elem
  float* coeff    = out + 2097153;             // 512*32768 elems

  char*   ws       = (char*)d_ws;
  double* loss_acc = (double*)ws;                                   // 8 B
  double* Dd       = (double*)(ws + 4096);                          // 256 KiB
  double* nrm2     = (double*)(ws + 4096 + (size_t)NATOM*MDIM*8);   // 4 KiB
  double* G        = (double*)(ws + 272384);                        // 2 MiB
  const size_t need = 272384 + (size_t)NATOM * NATOM * 8;

  hipMemsetAsync(coeff, 0, (size_t)NATOM * NSIG * sizeof(float), stream);
  prep_kernel<<<2, 256, 0, stream>>>(D, Dd, nrm2, loss_acc);

  if (ws_size >= need) {
    gram_kernel<<<NATOM, NATOM, 0, stream>>>(Dd, G);
    omp2_kernel<<<NSIG / 64, 512, 0, stream>>>(z_e, Dd, nrm2, G, z_dl, coeff, loss_acc);
  } else {
    omp_direct_kernel<<<NSIG / 64, 512, 0, stream>>>(z_e, Dd, nrm2, z_dl, coeff, loss_acc);
  }
  finalize_kernel<<<1, 1, 0, stream>>>(loss_acc, loss_out);
}

// Round 3
// 302.736 us; speedup vs baseline: 2.8264x; 1.9251x over previous
//
#include <hip/hip_runtime.h>
#include <stdint.h>

#define NSIG   32768
#define NATOM  512
#define MDIM   64
#define SPAR   5
#define EPS    1e-10

// ---------------- prep: normalize dictionary into fp64, compute atom norms ----
__global__ __launch_bounds__(256) void prep_kernel(const float* __restrict__ D,
                                                   double* __restrict__ Dd,
                                                   double* __restrict__ nrm2,
                                                   double* __restrict__ loss_acc) {
  int n = blockIdx.x * blockDim.x + threadIdx.x;
  if (n == 0) loss_acc[0] = 0.0;
  if (n >= NATOM) return;
  double ss = 0.0;
  for (int c = 0; c < MDIM; ++c) {
    double v = (double)D[c * NATOM + n];
    ss += v * v;
  }
  double norm = sqrt(ss);
  if (norm < 1e-10) norm = 1e-10;
  double s2 = 0.0;
  for (int c = 0; c < MDIM; ++c) {
    double v = (double)D[c * NATOM + n] / norm;
    Dd[(size_t)n * MDIM + c] = v;
    s2 += v * v;
  }
  nrm2[n] = s2;
}

// ---------------- Gram matrix G = Dn^T Dn (fp64, 512x512) --------------------
__global__ __launch_bounds__(512) void gram_kernel(const double* __restrict__ Dd,
                                                   double* __restrict__ G) {
  int i = blockIdx.x;
  int j = threadIdx.x;
  const double* di = Dd + ((size_t)i << 6);
  const double* dj = Dd + ((size_t)j << 6);
  double s = 0.0;
#pragma unroll
  for (int c = 0; c < MDIM; ++c) s += di[c] * dj[c];
  G[(size_t)i * NATOM + j] = s;
}

// ---------------- main OMP kernel (Gram recursion, lane-pair atom split) ------
// block = 512 threads = 8 waves, 32 signals/block. lane&31 = signal, lane>>5 =
// atom-half. Lane owns 32 atoms: base = w*64 + half*32, cor[32] in registers.
// D staged through LDS in 8-dim chunks with broadcast-friendly layout.
__global__ __launch_bounds__(512, 2) void omp3_kernel(const float* __restrict__ z_e,
                                                      const double* __restrict__ Dd,
                                                      const double* __restrict__ nrm2,
                                                      const double* __restrict__ G,
                                                      float* __restrict__ z_dl,
                                                      float* __restrict__ coeff,
                                                      double* __restrict__ loss_acc) {
  __shared__ double xs[MDIM][32];        // 16 KiB  x fp64 [dim][sig]
  __shared__ double dch[NATOM * 8];      // 32 KiB  D chunk, atom-major [atom][8]
  __shared__ double s_best[8][32];       // 2 KiB
  __shared__ double s_corr[8][32];       // 2 KiB
  __shared__ int    s_idx[8][32];        // 1 KiB

  const int tid  = threadIdx.x;
  const int w    = tid >> 6;             // wave 0..7
  const int lane = tid & 63;
  const int sig  = lane & 31;            // signal within block
  const int half = lane >> 5;            // atom-half 0/1
  const int base = w * 64 + half * 32;   // this lane's 32-atom range
  const int l    = blockIdx.x;           // t>>5 ; b = sig ; t = blockIdx*32+sig

  // ---- stage x (fp64) into LDS: 64 dims x 32 sigs, 4 elems/thread ----
#pragma unroll
  for (int r = 0; r < 4; ++r) {
    int idx = tid + r * 512;
    int c = idx >> 5, s = idx & 31;
    xs[c][s] = (double)z_e[(size_t)s * (MDIM * 1024) + (size_t)c * 1024 + l];
  }

  double cor[32];
#pragma unroll
  for (int k = 0; k < 32; ++k) cor[k] = 0.0;

  // ---- phase 1: cor[k] = <D[base+k], x>, D staged per 8-dim chunk ----
  for (int cd = 0; cd < MDIM; cd += 8) {
    __syncthreads();   // prev chunk reads done (also covers xs staging, iter 0)
    // stage: 4 passes, 4-lane groups write one atom row (linear LDS stream)
#pragma unroll
    for (int p = 0; p < 4; ++p) {
      int a = (tid >> 2) + p * 128;
      double2 v = *(const double2*)(Dd + ((size_t)a << 6) + cd + (tid & 3) * 2);
      ((double2*)dch)[p * 512 + tid] = v;
    }
    __syncthreads();
    double x8[8];
#pragma unroll
    for (int j = 0; j < 8; ++j) x8[j] = xs[cd + j][sig];
#pragma unroll
    for (int k = 0; k < 32; ++k) {
      const double2* dr = (const double2*)&dch[(base + k) * 8];
      double2 d0 = dr[0], d1 = dr[1], d2 = dr[2], d3 = dr[3];
      cor[k] += d0.x * x8[0] + d0.y * x8[1] + d1.x * x8[2] + d1.y * x8[3]
              + d2.x * x8[4] + d2.y * x8[5] + d3.x * x8[6] + d3.y * x8[7];
    }
  }
  __syncthreads();

  unsigned int mw = 0xffffffffu;   // availability of this lane's 32 atoms
  int sel[SPAR];
  double al[SPAR];

#pragma unroll
  for (int it = 0; it < SPAR; ++it) {
    // local argmax over 32 atoms (ascending k, strict > => first-max)
    double best = -1.0, bcorr = 0.0;
    int bidx = base;
#pragma unroll
    for (int k = 0; k < 32; ++k) {
      double aa = fabs(cor[k]);
      bool avail = (mw >> k) & 1u;
      bool better = avail && (aa > best);
      best  = better ? aa : best;
      bcorr = better ? cor[k] : bcorr;
      bidx  = better ? (base + k) : bidx;
    }
    // combine atom-halves (lane ^ 32); tie -> lower atom index (first-max)
    {
      double obest = __shfl_xor(best, 32);
      double ocorr = __shfl_xor(bcorr, 32);
      int    oidx  = __shfl_xor(bidx, 32);
      bool take = (obest > best) || (obest == best && oidx < bidx);
      best  = take ? obest : best;
      bcorr = take ? ocorr : bcorr;
      bidx  = take ? oidx  : bidx;
    }
    if (half == 0) {
      s_best[w][sig] = best;
      s_corr[w][sig] = bcorr;
      s_idx[w][sig]  = bidx;
    }
    __syncthreads();
    // global winner, identical in every thread (ascending w => first-max;
    // wave atom ranges are contiguous ascending)
    double gbest = -2.0, gcorr = 0.0;
    int gidx = 0;
#pragma unroll
    for (int w2 = 0; w2 < 8; ++w2) {
      double cb = s_best[w2][sig];
      double cc = s_corr[w2][sig];
      int    ci = s_idx[w2][sig];
      bool better = cb > gbest;
      gbest = better ? cb : gbest;
      gcorr = better ? cc : gcorr;
      gidx  = better ? ci : gidx;
    }
    __syncthreads();

    double alpha = gcorr / (nrm2[gidx] + EPS);
    if ((gidx >> 5) == (base >> 5)) mw &= ~(1u << (gidx & 31));
    if (w == 0 && half == 0)
      coeff[(size_t)gidx * NSIG + (size_t)blockIdx.x * 32 + sig] = (float)alpha;
    sel[it] = gidx;
    al[it]  = alpha;

    if (it != SPAR - 1) {
      // exact identity: corr_{t+1} = corr_t - alpha * G[gidx, :]
      const double* gp = G + (size_t)gidx * NATOM + base;
#pragma unroll
      for (int k = 0; k < 32; ++k) cor[k] -= alpha * gp[k];
    }
  }

  // ---- epilogue: z_dl = sum_t al[t]*d_sel[t]; loss = sum (zv - x)^2 ----
  // thread handles (c = (tid>>5) + r*16, s = tid&31 == its own sig)
  double s2 = 0.0;
#pragma unroll
  for (int r = 0; r < 4; ++r) {
    int c = (tid >> 5) + r * 16;
    double v = al[0] * Dd[(((size_t)sel[0]) << 6) + c];
#pragma unroll
    for (int tt = 1; tt < SPAR; ++tt)
      v += al[tt] * Dd[(((size_t)sel[tt]) << 6) + c];
    float zv = (float)v;
    z_dl[((size_t)sig * MDIM + c) * 1024 + l] = zv;
    double diff = (double)zv - xs[c][sig];
    s2 += diff * diff;
  }
  for (int o = 32; o > 0; o >>= 1) s2 += __shfl_down(s2, o);
  if (lane == 0) atomicAdd(loss_acc, s2);
}

// ---------------- finalize loss ---------------------------------------------
__global__ void finalize_kernel(const double* __restrict__ loss_acc,
                                float* __restrict__ loss_out) {
  loss_out[0] = (float)(1.25 * loss_acc[0] / 2097152.0);
}

extern "C" void kernel_launch(void* const* d_in, const int* in_sizes, int n_in,
                              void* d_out, int out_size, void* d_ws, size_t ws_size,
                              hipStream_t stream) {
  const float* z_e = (const float*)d_in[0];
  const float* D   = (const float*)d_in[1];

  float* out      = (float*)d_out;
  float* z_dl     = out;                       // 2097152 elems
  float* loss_out = out + 2097152;             // 1 elem
  float* coeff    = out + 2097153;             // 512*32768 elems

  char*   ws       = (char*)d_ws;
  double* loss_acc = (double*)ws;                                   // 8 B
  double* Dd       = (double*)(ws + 4096);                          // 256 KiB
  double* nrm2     = (double*)(ws + 4096 + (size_t)NATOM*MDIM*8);   // 4 KiB
  double* G        = (double*)(ws + 272384);                        // 2 MiB

  hipMemsetAsync(coeff, 0, (size_t)NATOM * NSIG * sizeof(float), stream);
  prep_kernel<<<2, 256, 0, stream>>>(D, Dd, nrm2, loss_acc);
  gram_kernel<<<NATOM, NATOM, 0, stream>>>(Dd, G);
  omp3_kernel<<<NSIG / 32, 512, 0, stream>>>(z_e, Dd, nrm2, G, z_dl, coeff, loss_acc);
  finalize_kernel<<<1, 1, 0, stream>>>(loss_acc, loss_out);
}

// Round 4
// 281.115 us; speedup vs baseline: 3.0438x; 1.0769x over previous
//
#include <hip/hip_runtime.h>
#include <stdint.h>

#define NSIG   32768
#define NATOM  512
#define MDIM   64
#define SPAR   5
#define EPS    1e-10

// ---------------- prep: normalize dictionary into fp64 (transposed layout) ---
// Dt[dim][atom] fp64 (same layout as input D), nrm2[atom] = ||Dn col||^2
__global__ __launch_bounds__(512) void prep_kernel(const float* __restrict__ D,
                                                   double* __restrict__ Dt,
                                                   double* __restrict__ nrm2,
                                                   double* __restrict__ loss_acc) {
  int n = threadIdx.x;                 // atom 0..511
  if (n == 0) loss_acc[0] = 0.0;
  double ss = 0.0;
#pragma unroll 8
  for (int c = 0; c < MDIM; ++c) {
    double v = (double)D[c * NATOM + n];
    ss += v * v;
  }
  double norm = sqrt(ss);
  if (norm < 1e-10) norm = 1e-10;
  double s2 = 0.0;
#pragma unroll 8
  for (int c = 0; c < MDIM; ++c) {
    double v = (double)D[c * NATOM + n] / norm;
    Dt[(size_t)c * NATOM + n] = v;
    s2 += v * v;
  }
  nrm2[n] = s2;
}

// ---------------- Gram matrix G = Dn^T Dn (fp64, 512x512) --------------------
__global__ __launch_bounds__(512) void gram_kernel(const double* __restrict__ Dt,
                                                   double* __restrict__ G) {
  int i = blockIdx.x;     // uniform -> s_load path
  int j = threadIdx.x;    // coalesced
  double s = 0.0;
#pragma unroll 8
  for (int c = 0; c < MDIM; ++c)
    s += Dt[(size_t)c * NATOM + i] * Dt[(size_t)c * NATOM + j];
  G[(size_t)i * NATOM + j] = s;
}

// ---------------- main OMP kernel (register-blocked GEMM + Gram recursion) ---
// block = 512 threads = 8 waves, 32 signals/block.
// Thread tile: 8 atoms x 4 signals (cor[8][4] in regs).
//   w = tid>>6, lane = tid&63, sq = lane>>3 (sig-quad), aw = lane&7,
//   ao = w*8+aw (atom-oct 0..63), atoms [ao*8, ao*8+8), sigs [sq*4, sq*4+4).
__global__ __launch_bounds__(512, 2) void omp4_kernel(const float* __restrict__ z_e,
                                                      const double* __restrict__ Dt,
                                                      const double* __restrict__ nrm2,
                                                      const double* __restrict__ G,
                                                      float* __restrict__ z_dl,
                                                      float* __restrict__ coeff,
                                                      double* __restrict__ loss_acc) {
  __shared__ double xs[MDIM][32];          // 16 KiB  x fp64 [dim][sig]
  __shared__ double dch[NATOM * 8];        // 32 KiB  D chunk [dimj][atom], XOR-swizzled
  __shared__ double s_b[8][32];            // 2 KiB   per-wave best |corr|
  __shared__ double s_c[8][32];            // 2 KiB   per-wave best corr
  __shared__ int    s_i[8][32];            // 1 KiB   per-wave best idx
  __shared__ double s_al[SPAR][32];        // 1.25 KiB alpha history
  __shared__ int    s_sel[SPAR][32];       // 0.63 KiB sel history

  const int tid  = threadIdx.x;
  const int w    = tid >> 6;
  const int lane = tid & 63;
  const int sq   = lane >> 3;              // 0..7
  const int aw   = lane & 7;               // 0..7
  const int ao   = w * 8 + aw;             // 0..63
  const int abase = ao * 8;                // first of 8 atoms
  const int sigbase = sq * 4;              // first of 4 signals
  const int l = blockIdx.x;                // token l-index; sigs = b = 0..31

  // ---- stage x (fp64) into LDS: 64 dims x 32 sigs ----
#pragma unroll
  for (int r = 0; r < 4; ++r) {
    int idx = tid + r * 512;
    int c = idx >> 5, s = idx & 31;
    xs[c][s] = (double)z_e[(size_t)s * (MDIM * 1024) + (size_t)c * 1024 + l];
  }

  double cor[8][4];
#pragma unroll
  for (int a = 0; a < 8; ++a)
#pragma unroll
    for (int si = 0; si < 4; ++si) cor[a][si] = 0.0;

  // ---- phase 1: register-blocked GEMM cor = D^T x ----
  for (int cd = 0; cd < MDIM; cd += 8) {
    __syncthreads();                      // prior chunk consumed (and xs staged)
    const double2* src = (const double2*)(Dt + (size_t)cd * NATOM);
#pragma unroll
    for (int p = 0; p < 4; ++p) {
      int idx = tid + p * 512;            // 2048 double2 = 32 KiB chunk
      double2 v = src[idx];
      int bb = idx << 4;
      bb ^= ((bb >> 6) & 7) << 4;         // st-swizzle (bijective, conflict-free)
      *(double2*)((char*)dch + bb) = v;
    }
    __syncthreads();
#pragma unroll
    for (int j = 0; j < 8; ++j) {
      const int k = cd + j;
      double2 xa = *(const double2*)&xs[k][sigbase];
      double2 xb = *(const double2*)&xs[k][sigbase + 2];
      const int base = j * 4096 + ao * 64;
      const int sw = aw << 4;
      double2 d0 = *(const double2*)((const char*)dch + ((base +  0) ^ sw));
      double2 d1 = *(const double2*)((const char*)dch + ((base + 16) ^ sw));
      double2 d2 = *(const double2*)((const char*)dch + ((base + 32) ^ sw));
      double2 d3 = *(const double2*)((const char*)dch + ((base + 48) ^ sw));
      double dv[8] = {d0.x, d0.y, d1.x, d1.y, d2.x, d2.y, d3.x, d3.y};
      double xv[4] = {xa.x, xa.y, xb.x, xb.y};
#pragma unroll
      for (int a = 0; a < 8; ++a)
#pragma unroll
        for (int si = 0; si < 4; ++si)
          cor[a][si] += dv[a] * xv[si];
    }
  }

  // ---- iterations: argmax + Gram-recursion update ----
  unsigned int mk = 0xffffffffu;          // availability bit (a*4+si)

  for (int it = 0; it < SPAR; ++it) {
    double best[4], bco[4];
    int bix[4];
#pragma unroll
    for (int si = 0; si < 4; ++si) {
      best[si] = -1.0; bco[si] = 0.0; bix[si] = abase;
#pragma unroll
      for (int a = 0; a < 8; ++a) {
        double aa = fabs(cor[a][si]);
        bool ok = ((mk >> (a * 4 + si)) & 1u) && (aa > best[si]);
        best[si] = ok ? aa : best[si];
        bco[si]  = ok ? cor[a][si] : bco[si];
        bix[si]  = ok ? (abase + a) : bix[si];
      }
    }
    // butterfly across the 8-lane atom group (offsets 1,2,4); tie -> lower idx
#pragma unroll
    for (int o = 1; o < 8; o <<= 1) {
#pragma unroll
      for (int si = 0; si < 4; ++si) {
        double ob = __shfl_xor(best[si], o);
        double oc = __shfl_xor(bco[si], o);
        int    oi = __shfl_xor(bix[si], o);
        bool take = (ob > best[si]) || (ob == best[si] && oi < bix[si]);
        best[si] = take ? ob : best[si];
        bco[si]  = take ? oc : bco[si];
        bix[si]  = take ? oi : bix[si];
      }
    }
    __syncthreads();                      // protect s_b/s_c/s_i from prior readers
    if (aw == 0) {
#pragma unroll
      for (int si = 0; si < 4; ++si) {
        s_b[w][sigbase + si] = best[si];
        s_c[w][sigbase + si] = bco[si];
        s_i[w][sigbase + si] = bix[si];
      }
    }
    __syncthreads();
    // global winner per sig (waves are atom-ascending; strict > => first-max)
#pragma unroll
    for (int si = 0; si < 4; ++si) {
      double gb = -2.0, gc = 0.0;
      int gi = 0;
#pragma unroll
      for (int w2 = 0; w2 < 8; ++w2) {
        double cb = s_b[w2][sigbase + si];
        double cc = s_c[w2][sigbase + si];
        int    ci = s_i[w2][sigbase + si];
        bool better = cb > gb;
        gb = better ? cb : gb;
        gc = better ? cc : gc;
        gi = better ? ci : gi;
      }
      double alpha = gc / (nrm2[gi] + EPS);
      if (w == 0 && aw == 0) {
        s_sel[it][sigbase + si] = gi;
        s_al[it][sigbase + si]  = alpha;
      }
      if ((gi >> 3) == ao) mk &= ~(1u << ((gi & 7) * 4 + si));
      if (it != SPAR - 1) {
        const double2* gp = (const double2*)(G + (size_t)gi * NATOM + abase);
        double2 g0 = gp[0], g1 = gp[1], g2 = gp[2], g3 = gp[3];
        cor[0][si] -= alpha * g0.x;  cor[1][si] -= alpha * g0.y;
        cor[2][si] -= alpha * g1.x;  cor[3][si] -= alpha * g1.y;
        cor[4][si] -= alpha * g2.x;  cor[5][si] -= alpha * g2.y;
        cor[6][si] -= alpha * g3.x;  cor[7][si] -= alpha * g3.y;
      }
    }
  }
  __syncthreads();                        // publish s_sel/s_al (incl. last iter)

  // ---- epilogue A: z_dl + loss (thread -> (c = tid>>5 + r*16, s = tid&31)) --
  double s2 = 0.0;
#pragma unroll
  for (int r = 0; r < 4; ++r) {
    int c = (tid >> 5) + r * 16;
    int s = tid & 31;
    double v = s_al[0][s] * Dt[(size_t)c * NATOM + s_sel[0][s]];
#pragma unroll
    for (int tt = 1; tt < SPAR; ++tt)
      v += s_al[tt][s] * Dt[(size_t)c * NATOM + s_sel[tt][s]];
    float zv = (float)v;
    z_dl[((size_t)s * MDIM + c) * 1024 + l] = zv;
    double diff = (double)zv - xs[c][s];
    s2 += diff * diff;
  }
#pragma unroll
  for (int o = 32; o > 0; o >>= 1) s2 += __shfl_down(s2, o);
  if (lane == 0) atomicAdd(loss_acc, s2);

  // ---- epilogue B: full coeff rows (thread = atom tid; no memset needed) ----
  {
    float vals[32];
#pragma unroll
    for (int s = 0; s < 32; ++s) {
      float v = 0.0f;
#pragma unroll
      for (int tt = 0; tt < SPAR; ++tt)
        v = (s_sel[tt][s] == tid) ? (float)s_al[tt][s] : v;
      vals[s] = v;
    }
    float* cp = coeff + (size_t)tid * NSIG + (size_t)blockIdx.x * 32;
#pragma unroll
    for (int p = 0; p < 8; ++p) {
      float4 q = make_float4(vals[p*4+0], vals[p*4+1], vals[p*4+2], vals[p*4+3]);
      *(float4*)(cp + p * 4) = q;
    }
  }
}

// ---------------- finalize loss ---------------------------------------------
__global__ void finalize_kernel(const double* __restrict__ loss_acc,
                                float* __restrict__ loss_out) {
  loss_out[0] = (float)(1.25 * loss_acc[0] / 2097152.0);
}

extern "C" void kernel_launch(void* const* d_in, const int* in_sizes, int n_in,
                              void* d_out, int out_size, void* d_ws, size_t ws_size,
                              hipStream_t stream) {
  const float* z_e = (const float*)d_in[0];
  const float* D   = (const float*)d_in[1];

  float* out      = (float*)d_out;
  float* z_dl     = out;                       // 2097152 elems
  float* loss_out = out + 2097152;             // 1 elem
  float* coeff    = out + 2097153;             // 512*32768 elems

  char*   ws       = (char*)d_ws;
  double* loss_acc = (double*)ws;                                   // 8 B
  double* Dt       = (double*)(ws + 4096);                          // 256 KiB
  double* nrm2     = (double*)(ws + 4096 + (size_t)NATOM*MDIM*8);   // 4 KiB
  double* G        = (double*)(ws + 272384);                        // 2 MiB

  prep_kernel<<<1, 512, 0, stream>>>(D, Dt, nrm2, loss_acc);
  gram_kernel<<<NATOM, NATOM, 0, stream>>>(Dt, G);
  omp4_kernel<<<NSIG / 32, 512, 0, stream>>>(z_e, Dt, nrm2, G, z_dl, coeff, loss_acc);
  finalize_kernel<<<1, 1, 0, stream>>>(loss_acc, loss_out);
}

// Round 5
// 270.192 us; speedup vs baseline: 3.1669x; 1.0404x over previous
//
#include <hip/hip_runtime.h>
#include <stdint.h>

#define NSIG   32768
#define NATOM  512
#define MDIM   64
#define SPAR   5
#define EPS    1e-10

// ---------------- prep: normalize dictionary into fp64 (transposed layout) ---
__global__ __launch_bounds__(512) void prep_kernel(const float* __restrict__ D,
                                                   double* __restrict__ Dt,
                                                   double* __restrict__ nrm2) {
  int n = threadIdx.x;                 // atom 0..511
  double ss = 0.0;
#pragma unroll 8
  for (int c = 0; c < MDIM; ++c) {
    double v = (double)D[c * NATOM + n];
    ss += v * v;
  }
  double norm = sqrt(ss);
  if (norm < 1e-10) norm = 1e-10;
  double s2 = 0.0;
#pragma unroll 8
  for (int c = 0; c < MDIM; ++c) {
    double v = (double)D[c * NATOM + n] / norm;
    Dt[(size_t)c * NATOM + n] = v;
    s2 += v * v;
  }
  nrm2[n] = s2;
}

// ---------------- Gram matrix G = Dn^T Dn (fp64, 512x512) --------------------
__global__ __launch_bounds__(512) void gram_kernel(const double* __restrict__ Dt,
                                                   double* __restrict__ G) {
  int i = blockIdx.x;     // uniform -> s_load path
  int j = threadIdx.x;    // coalesced
  double s = 0.0;
#pragma unroll 8
  for (int c = 0; c < MDIM; ++c)
    s += Dt[(size_t)c * NATOM + i] * Dt[(size_t)c * NATOM + j];
  G[(size_t)i * NATOM + j] = s;
}

// ---------------- main OMP kernel -------------------------------------------
// block = 512 threads = 8 waves, 32 signals/block (one token-l per block).
// Thread tile: 8 atoms x 4 signals. Phase-1 streams Dt from L2 (no staging,
// no barriers). Selection: packed u64 keys, single-wave finalize.
__global__ __launch_bounds__(512, 2) void omp5_kernel(const float* __restrict__ z_e,
                                                      const double* __restrict__ Dt,
                                                      const double* __restrict__ nrm2,
                                                      const double* __restrict__ G,
                                                      float* __restrict__ z_dl,
                                                      float* __restrict__ coeff,
                                                      double* __restrict__ partial) {
  __shared__ double xs[MDIM][32];                 // 16 KiB  x fp64 [dim][sig]
  __shared__ unsigned long long s_key[8][32];     // 2 KiB   per-wave winner keys
  __shared__ double s_al[SPAR][32];               // 1.25 KiB alpha history
  __shared__ int    s_sel[SPAR][32];              // 0.625 KiB sel history
  __shared__ double s_red[8];                     // loss partials per wave

  const int tid  = threadIdx.x;
  const int w    = tid >> 6;
  const int lane = tid & 63;
  const int sq   = lane >> 3;              // 0..7 signal-quad
  const int aw   = lane & 7;               // 0..7 atom-oct-in-wave
  const int ao   = w * 8 + aw;             // 0..63
  const int abase = ao * 8;                // first of this thread's 8 atoms
  const int sigbase = sq * 4;              // first of this thread's 4 signals
  const int bid = blockIdx.x;
  const int l   = ((bid & 7) << 7) | (bid >> 3);   // XCD swizzle (bijective, 1024=8*128)

  // ---- stage x (fp64) into LDS: 64 dims x 32 sigs ----
#pragma unroll
  for (int r = 0; r < 4; ++r) {
    int idx = tid + r * 512;
    int c = idx >> 5, s = idx & 31;
    xs[c][s] = (double)z_e[(size_t)s * (MDIM * 1024) + (size_t)c * 1024 + l];
  }
  __syncthreads();

  double cor[8][4];
#pragma unroll
  for (int a = 0; a < 8; ++a)
#pragma unroll
    for (int si = 0; si < 4; ++si) cor[a][si] = 0.0;

  // ---- phase 1: cor += Dt[k][abase..+8] * x[k][sigbase..+4], streamed from L2
#pragma unroll 4
  for (int k = 0; k < MDIM; ++k) {
    const double2* dr = (const double2*)(Dt + (size_t)k * NATOM + abase);
    double2 d0 = dr[0], d1 = dr[1], d2 = dr[2], d3 = dr[3];
    double2 xa = *(const double2*)&xs[k][sigbase];
    double2 xb = *(const double2*)&xs[k][sigbase + 2];
    double dv[8] = {d0.x, d0.y, d1.x, d1.y, d2.x, d2.y, d3.x, d3.y};
    double xv[4] = {xa.x, xa.y, xb.x, xb.y};
#pragma unroll
    for (int a = 0; a < 8; ++a)
#pragma unroll
      for (int si = 0; si < 4; ++si)
        cor[a][si] += dv[a] * xv[si];
  }

  // ---- iterations ----
  unsigned int mk = 0xffffffffu;            // availability bit (a*4+si)

  for (int it = 0; it < SPAR; ++it) {
    // local argmax over 8 atoms per si; track (|c| double, hi-word, idx-enc)
    unsigned long long key[4];
#pragma unroll
    for (int si = 0; si < 4; ++si) {
      double babs = -1.0;
      unsigned int bhi = 0;
      int benc = 0;
#pragma unroll
      for (int a = 0; a < 8; ++a) {
        double c = cor[a][si];
        double ac = fabs(c);
        bool ok = ((mk >> (a * 4 + si)) & 1u) && (ac > babs);
        babs = ok ? ac : babs;
        bhi  = ok ? (unsigned int)__double2hiint(c) : bhi;
        benc = ok ? (511 - (abase + a)) : benc;
      }
      unsigned int khi = (unsigned int)__double2hiint(babs);
      unsigned int klo = ((unsigned int)__double2loint(babs) & 0xFFFFFC00u)
                       | ((bhi >> 22) & 0x200u) | (unsigned int)benc;
      key[si] = ((unsigned long long)khi << 32) | klo;
    }
    // butterfly across the 8-lane atom group: u64 max
#pragma unroll
    for (int o = 1; o < 8; o <<= 1) {
#pragma unroll
      for (int si = 0; si < 4; ++si) {
        unsigned long long ok2 = __shfl_xor(key[si], o);
        key[si] = (ok2 > key[si]) ? ok2 : key[si];
      }
    }
    if (aw == 0) {
#pragma unroll
      for (int si = 0; si < 4; ++si) s_key[w][sigbase + si] = key[si];
    }
    __syncthreads();                        // (A) keys published
    if (tid < 32) {                         // wave 0, lane = sig
      unsigned long long kk = s_key[0][tid];
#pragma unroll
      for (int w2 = 1; w2 < 8; ++w2) {
        unsigned long long o = s_key[w2][tid];
        kk = (o > kk) ? o : kk;
      }
      int gi = 511 - (int)(kk & 0x1FF);
      double c = __longlong_as_double((long long)(kk & ~0x3FFull));
      if (kk & 0x200ull) c = -c;
      s_sel[it][tid] = gi;
      s_al[it][tid]  = c / (nrm2[gi] + EPS);
    }
    __syncthreads();                        // (B) winner published
    if (it != SPAR - 1) {
#pragma unroll
      for (int si = 0; si < 4; ++si) {
        int gi = s_sel[it][sigbase + si];
        double alpha = s_al[it][sigbase + si];
        int d = gi - abase;
        if ((unsigned)d < 8u) mk &= ~(1u << (d * 4 + si));
        const double2* gp = (const double2*)(G + (size_t)gi * NATOM + abase);
        double2 g0 = gp[0], g1 = gp[1], g2 = gp[2], g3 = gp[3];
        cor[0][si] -= alpha * g0.x;  cor[1][si] -= alpha * g0.y;
        cor[2][si] -= alpha * g1.x;  cor[3][si] -= alpha * g1.y;
        cor[4][si] -= alpha * g2.x;  cor[5][si] -= alpha * g2.y;
        cor[6][si] -= alpha * g3.x;  cor[7][si] -= alpha * g3.y;
      }
    }
  }

  // ---- epilogue A: z_dl + loss ----
  double s2 = 0.0;
#pragma unroll
  for (int r = 0; r < 4; ++r) {
    int c = (tid >> 5) + r * 16;
    int s = tid & 31;
    double v = s_al[0][s] * Dt[(size_t)c * NATOM + s_sel[0][s]];
#pragma unroll
    for (int tt = 1; tt < SPAR; ++tt)
      v += s_al[tt][s] * Dt[(size_t)c * NATOM + s_sel[tt][s]];
    float zv = (float)v;
    z_dl[((size_t)s * MDIM + c) * 1024 + l] = zv;
    double diff = (double)zv - xs[c][s];
    s2 += diff * diff;
  }
#pragma unroll
  for (int o = 32; o > 0; o >>= 1) s2 += __shfl_down(s2, o);
  if (lane == 0) s_red[w] = s2;
  __syncthreads();
  if (tid == 0) {
    double tsum = 0.0;
#pragma unroll
    for (int w2 = 0; w2 < 8; ++w2) tsum += s_red[w2];
    partial[bid] = tsum;
  }

  // ---- epilogue B: full coeff rows (thread = atom tid; zeros included) ----
  {
    float vals[32];
#pragma unroll
    for (int s = 0; s < 32; ++s) {
      float v = 0.0f;
#pragma unroll
      for (int tt = 0; tt < SPAR; ++tt)
        v = (s_sel[tt][s] == tid) ? (float)s_al[tt][s] : v;
      vals[s] = v;
    }
    float* cp = coeff + (size_t)tid * NSIG + (size_t)l * 32;
#pragma unroll
    for (int p = 0; p < 8; ++p) {
      float4 q = make_float4(vals[p*4+0], vals[p*4+1], vals[p*4+2], vals[p*4+3]);
      *(float4*)(cp + p * 4) = q;
    }
  }
}

// ---------------- finalize loss ---------------------------------------------
__global__ __launch_bounds__(64) void finalize_kernel(const double* __restrict__ partial,
                                                      float* __restrict__ loss_out) {
  double s = 0.0;
  for (int i = threadIdx.x; i < 1024; i += 64) s += partial[i];
#pragma unroll
  for (int o = 32; o > 0; o >>= 1) s += __shfl_down(s, o);
  if (threadIdx.x == 0) loss_out[0] = (float)(1.25 * s / 2097152.0);
}

extern "C" void kernel_launch(void* const* d_in, const int* in_sizes, int n_in,
                              void* d_out, int out_size, void* d_ws, size_t ws_size,
                              hipStream_t stream) {
  const float* z_e = (const float*)d_in[0];
  const float* D   = (const float*)d_in[1];

  float* out      = (float*)d_out;
  float* z_dl     = out;                       // 2097152 elems
  float* loss_out = out + 2097152;             // 1 elem
  float* coeff    = out + 2097153;             // 512*32768 elems

  char*   ws      = (char*)d_ws;
  double* partial = (double*)ws;                                   // 8 KiB (1024 f64)
  double* Dt      = (double*)(ws + 8192);                          // 256 KiB
  double* nrm2    = (double*)(ws + 8192 + (size_t)NATOM*MDIM*8);   // 4 KiB
  double* G       = (double*)(ws + 8192 + (size_t)NATOM*MDIM*8 + 4096); // 2 MiB

  prep_kernel<<<1, 512, 0, stream>>>(D, Dt, nrm2);
  gram_kernel<<<NATOM, NATOM, 0, stream>>>(Dt, G);
  omp5_kernel<<<NSIG / 32, 512, 0, stream>>>(z_e, Dt, nrm2, G, z_dl, coeff, partial);
  finalize_kernel<<<1, 64, 0, stream>>>(partial, loss_out);
}

// Round 6
// 181.856 us; speedup vs baseline: 4.7052x; 1.4857x over previous
//
#include <hip/hip_runtime.h>
#include <stdint.h>

#define NSIG   32768
#define NATOM  512
#define MDIM   64
#define SPAR   5
#define EPS    1e-10

// ---------------- prep: normalize dictionary into fp64 (transposed layout) ---
__global__ __launch_bounds__(512) void prep_kernel(const float* __restrict__ D,
                                                   double* __restrict__ Dt,
                                                   double* __restrict__ nrm2) {
  int n = threadIdx.x;                 // atom 0..511
  double ss = 0.0;
#pragma unroll 8
  for (int c = 0; c < MDIM; ++c) {
    double v = (double)D[c * NATOM + n];
    ss += v * v;
  }
  double norm = sqrt(ss);
  if (norm < 1e-10) norm = 1e-10;
  double s2 = 0.0;
#pragma unroll 8
  for (int c = 0; c < MDIM; ++c) {
    double v = (double)D[c * NATOM + n] / norm;
    Dt[(size_t)c * NATOM + n] = v;
    s2 += v * v;
  }
  nrm2[n] = s2;
}

// ---------------- Gram matrix G = Dn^T Dn (fp64, 512x512) --------------------
__global__ __launch_bounds__(512) void gram_kernel(const double* __restrict__ Dt,
                                                   double* __restrict__ G) {
  int i = blockIdx.x;
  int j = threadIdx.x;
  double s = 0.0;
#pragma unroll 8
  for (int c = 0; c < MDIM; ++c)
    s += Dt[(size_t)c * NATOM + i] * Dt[(size_t)c * NATOM + j];
  G[(size_t)i * NATOM + j] = s;
}

// ---------------- repack: xw[l][c][b] = z_e[b][c][l] (f32) -------------------
__global__ __launch_bounds__(512) void repack_kernel(const float* __restrict__ z_e,
                                                     float* __restrict__ xw) {
  int bid = blockIdx.x;
  int l = ((bid & 7) << 7) | (bid >> 3);   // same XCD swizzle as main kernel
#pragma unroll
  for (int p = 0; p < 4; ++p) {
    int idx = threadIdx.x + p * 512;       // 0..2047 = c*32+b
    int c = idx >> 5, b = idx & 31;
    xw[(size_t)l * 2048 + idx] = z_e[(size_t)b * 65536 + (size_t)c * 1024 + l];
  }
}

// ---------------- main OMP kernel (wave-autonomous, 8 atoms x 8 sigs) --------
// block = 256 threads = 4 waves; wave w owns sigs b in [8w,8w+8) of token l.
// Lane owns atoms [lane*8, lane*8+8) -> wave covers all 512 atoms.
__global__ __launch_bounds__(256) void omp6_kernel(const float* __restrict__ xw,
                                                   const double* __restrict__ Dt,
                                                   const double* __restrict__ nrm2,
                                                   const double* __restrict__ G,
                                                   float* __restrict__ z_dl,
                                                   float* __restrict__ coeff,
                                                   double* __restrict__ partial) {
  __shared__ double s_al[SPAR][32];
  __shared__ int    s_sel[SPAR][32];
  __shared__ double s_red[4];

  const int tid  = threadIdx.x;
  const int w    = __builtin_amdgcn_readfirstlane(tid >> 6);
  const int lane = tid & 63;
  const int abase = lane << 3;             // lane's first atom
  const int bid = blockIdx.x;
  const int l   = ((bid & 7) << 7) | (bid >> 3);   // XCD swizzle (bijective)

  const float* xp = xw + (size_t)l * 2048 + (w << 3);   // + k*32, wave-uniform

  double cor[8][8];                        // [atom][sig]
#pragma unroll
  for (int a = 0; a < 8; ++a)
#pragma unroll
    for (int si = 0; si < 8; ++si) cor[a][si] = 0.0;

  // ---- phase 1: cor[a][si] += Dt[k][abase+a] * x[k][si], 1-deep pipelined ---
  const double* dbase = Dt + abase;
  double2 d0, d1, d2, d3;
  float4 xa, xb;
  {
    const double2* dr = (const double2*)dbase;
    d0 = dr[0]; d1 = dr[1]; d2 = dr[2]; d3 = dr[3];
    xa = *(const float4*)xp; xb = *(const float4*)(xp + 4);
  }
  for (int k = 0; k < MDIM; ++k) {
    double dv[8] = {d0.x, d0.y, d1.x, d1.y, d2.x, d2.y, d3.x, d3.y};
    double xv[8] = {(double)xa.x, (double)xa.y, (double)xa.z, (double)xa.w,
                    (double)xb.x, (double)xb.y, (double)xb.z, (double)xb.w};
    if (k + 1 < MDIM) {
      const double2* dr = (const double2*)(dbase + (size_t)(k + 1) * NATOM);
      d0 = dr[0]; d1 = dr[1]; d2 = dr[2]; d3 = dr[3];
      xa = *(const float4*)(xp + (k + 1) * 32);
      xb = *(const float4*)(xp + (k + 1) * 32 + 4);
    }
#pragma unroll
    for (int a = 0; a < 8; ++a)
#pragma unroll
      for (int si = 0; si < 8; ++si)
        cor[a][si] += dv[a] * xv[si];
  }

  // ---- iterations (barrier-free, wave-autonomous) ----
  unsigned long long mk = ~0ull;           // availability bit (a*8+si)

  for (int it = 0; it < SPAR; ++it) {
    unsigned long long key[8];
#pragma unroll
    for (int si = 0; si < 8; ++si) {
      double babs = -1.0;
      unsigned int bhi = 0;
      int benc = 0;
#pragma unroll
      for (int a = 0; a < 8; ++a) {
        double c = cor[a][si];
        double ac = fabs(c);
        bool ok = ((mk >> ((a << 3) + si)) & 1ull) && (ac > babs);
        babs = ok ? ac : babs;
        bhi  = ok ? (unsigned int)__double2hiint(c) : bhi;
        benc = ok ? (511 - (abase + a)) : benc;
      }
      unsigned int khi = (unsigned int)__double2hiint(babs);
      unsigned int klo = ((unsigned int)__double2loint(babs) & 0xFFFFFC00u)
                       | ((bhi >> 22) & 0x200u) | (unsigned int)benc;
      key[si] = ((unsigned long long)khi << 32) | klo;
    }
    // stage A: reduce within 8-lane groups, all 8 sig-keys
#pragma unroll
    for (int o = 1; o < 8; o <<= 1) {
#pragma unroll
      for (int si = 0; si < 8; ++si) {
        unsigned long long ok2 = __shfl_xor(key[si], o);
        if (ok2 > key[si]) key[si] = ok2;
      }
    }
    // stage B: lane takes sig (lane&7), reduce across groups
    unsigned long long kk = key[0];
#pragma unroll
    for (int si = 1; si < 8; ++si) kk = ((lane & 7) == si) ? key[si] : kk;
#pragma unroll
    for (int o = 8; o < 64; o <<= 1) {
      unsigned long long ok2 = __shfl_xor(kk, o);
      if (ok2 > kk) kk = ok2;
    }
    // broadcast winners of all 8 sigs to all lanes
    unsigned long long wk[8];
#pragma unroll
    for (int si = 0; si < 8; ++si) wk[si] = __shfl(kk, si);

    // decode + publish + Gram update
#pragma unroll
    for (int si = 0; si < 8; ++si) {
      unsigned long long kv = wk[si];
      int gi = 511 - (int)(kv & 0x1FF);
      double c = __longlong_as_double((long long)(kv & ~0x3FFull));
      c = (kv & 0x200ull) ? -c : c;
      int giu = __builtin_amdgcn_readfirstlane(gi);
      double alpha = c / (nrm2[giu] + EPS);
      int d = gi - abase;
      if ((unsigned)d < 8u) mk &= ~(1ull << ((d << 3) + si));
      if (lane == si) {
        s_sel[it][(w << 3) + si] = giu;
        s_al[it][(w << 3) + si]  = alpha;
      }
      if (it != SPAR - 1) {
        const double2* gp = (const double2*)(G + (size_t)giu * NATOM + abase);
        double2 g0 = gp[0], g1 = gp[1], g2 = gp[2], g3 = gp[3];
        cor[0][si] -= alpha * g0.x;  cor[1][si] -= alpha * g0.y;
        cor[2][si] -= alpha * g1.x;  cor[3][si] -= alpha * g1.y;
        cor[4][si] -= alpha * g2.x;  cor[5][si] -= alpha * g2.y;
        cor[6][si] -= alpha * g3.x;  cor[7][si] -= alpha * g3.y;
      }
    }
  }
  __syncthreads();                         // publish all waves' s_sel/s_al

  // ---- epilogue A: z_dl + loss ----
  const int s  = tid & 31;
  const int c0 = tid >> 5;                 // 0..7
  double s2 = 0.0;
#pragma unroll
  for (int r = 0; r < 8; ++r) {
    int c = c0 + (r << 3);
    double v = s_al[0][s] * Dt[(size_t)c * NATOM + s_sel[0][s]];
#pragma unroll
    for (int tt = 1; tt < SPAR; ++tt)
      v += s_al[tt][s] * Dt[(size_t)c * NATOM + s_sel[tt][s]];
    float zv = (float)v;
    z_dl[((size_t)s * MDIM + c) * 1024 + l] = zv;
    double x = (double)xw[(size_t)l * 2048 + (c << 5) + s];
    double diff = (double)zv - x;
    s2 += diff * diff;
  }
#pragma unroll
  for (int o = 32; o > 0; o >>= 1) s2 += __shfl_down(s2, o);
  if (lane == 0) s_red[w] = s2;
  __syncthreads();
  if (tid == 0) partial[bid] = ((s_red[0] + s_red[1]) + (s_red[2] + s_red[3]));

  // ---- epilogue B: coeff, wave-coalesced (thread = (sig s, atom range g)) ---
  {
    int g = tid >> 5;                      // 0..7 -> atoms [g*64, g*64+64)
    int sl[SPAR]; float av[SPAR];
#pragma unroll
    for (int tt = 0; tt < SPAR; ++tt) {
      sl[tt] = s_sel[tt][s];
      av[tt] = (float)s_al[tt][s];
    }
    float* cp = coeff + (size_t)(g << 6) * NSIG + ((size_t)l << 5) + s;
#pragma unroll 8
    for (int j = 0; j < 64; ++j) {
      int a = (g << 6) + j;
      float v = 0.0f;
#pragma unroll
      for (int tt = 0; tt < SPAR; ++tt) v = (sl[tt] == a) ? av[tt] : v;
      cp[(size_t)j * NSIG] = v;
    }
  }
}

// ---------------- fallback: R5 kernel (used when ws too small for xw) --------
__global__ __launch_bounds__(512, 2) void omp5_kernel(const float* __restrict__ z_e,
                                                      const double* __restrict__ Dt,
                                                      const double* __restrict__ nrm2,
                                                      const double* __restrict__ G,
                                                      float* __restrict__ z_dl,
                                                      float* __restrict__ coeff,
                                                      double* __restrict__ partial) {
  __shared__ double xs[MDIM][32];
  __shared__ unsigned long long s_key[8][32];
  __shared__ double s_al[SPAR][32];
  __shared__ int    s_sel[SPAR][32];
  __shared__ double s_red[8];

  const int tid  = threadIdx.x;
  const int w    = tid >> 6;
  const int lane = tid & 63;
  const int sq   = lane >> 3;
  const int aw   = lane & 7;
  const int ao   = w * 8 + aw;
  const int abase = ao * 8;
  const int sigbase = sq * 4;
  const int bid = blockIdx.x;
  const int l   = ((bid & 7) << 7) | (bid >> 3);

#pragma unroll
  for (int r = 0; r < 4; ++r) {
    int idx = tid + r * 512;
    int c = idx >> 5, s = idx & 31;
    xs[c][s] = (double)z_e[(size_t)s * (MDIM * 1024) + (size_t)c * 1024 + l];
  }
  __syncthreads();

  double cor[8][4];
#pragma unroll
  for (int a = 0; a < 8; ++a)
#pragma unroll
    for (int si = 0; si < 4; ++si) cor[a][si] = 0.0;

#pragma unroll 4
  for (int k = 0; k < MDIM; ++k) {
    const double2* dr = (const double2*)(Dt + (size_t)k * NATOM + abase);
    double2 d0 = dr[0], d1 = dr[1], d2 = dr[2], d3 = dr[3];
    double2 xa2 = *(const double2*)&xs[k][sigbase];
    double2 xb2 = *(const double2*)&xs[k][sigbase + 2];
    double dv[8] = {d0.x, d0.y, d1.x, d1.y, d2.x, d2.y, d3.x, d3.y};
    double xv[4] = {xa2.x, xa2.y, xb2.x, xb2.y};
#pragma unroll
    for (int a = 0; a < 8; ++a)
#pragma unroll
      for (int si = 0; si < 4; ++si)
        cor[a][si] += dv[a] * xv[si];
  }

  unsigned int mk = 0xffffffffu;
  for (int it = 0; it < SPAR; ++it) {
    unsigned long long key[4];
#pragma unroll
    for (int si = 0; si < 4; ++si) {
      double babs = -1.0;
      unsigned int bhi = 0;
      int benc = 0;
#pragma unroll
      for (int a = 0; a < 8; ++a) {
        double c = cor[a][si];
        double ac = fabs(c);
        bool ok = ((mk >> (a * 4 + si)) & 1u) && (ac > babs);
        babs = ok ? ac : babs;
        bhi  = ok ? (unsigned int)__double2hiint(c) : bhi;
        benc = ok ? (511 - (abase + a)) : benc;
      }
      unsigned int khi = (unsigned int)__double2hiint(babs);
      unsigned int klo = ((unsigned int)__double2loint(babs) & 0xFFFFFC00u)
                       | ((bhi >> 22) & 0x200u) | (unsigned int)benc;
      key[si] = ((unsigned long long)khi << 32) | klo;
    }
#pragma unroll
    for (int o = 1; o < 8; o <<= 1) {
#pragma unroll
      for (int si = 0; si < 4; ++si) {
        unsigned long long ok2 = __shfl_xor(key[si], o);
        key[si] = (ok2 > key[si]) ? ok2 : key[si];
      }
    }
    if (aw == 0) {
#pragma unroll
      for (int si = 0; si < 4; ++si) s_key[w][sigbase + si] = key[si];
    }
    __syncthreads();
    if (tid < 32) {
      unsigned long long kk = s_key[0][tid];
#pragma unroll
      for (int w2 = 1; w2 < 8; ++w2) {
        unsigned long long o = s_key[w2][tid];
        kk = (o > kk) ? o : kk;
      }
      int gi = 511 - (int)(kk & 0x1FF);
      double c = __longlong_as_double((long long)(kk & ~0x3FFull));
      if (kk & 0x200ull) c = -c;
      s_sel[it][tid] = gi;
      s_al[it][tid]  = c / (nrm2[gi] + EPS);
    }
    __syncthreads();
    if (it != SPAR - 1) {
#pragma unroll
      for (int si = 0; si < 4; ++si) {
        int gi = s_sel[it][sigbase + si];
        double alpha = s_al[it][sigbase + si];
        int d = gi - abase;
        if ((unsigned)d < 8u) mk &= ~(1u << (d * 4 + si));
        const double2* gp = (const double2*)(G + (size_t)gi * NATOM + abase);
        double2 g0 = gp[0], g1 = gp[1], g2 = gp[2], g3 = gp[3];
        cor[0][si] -= alpha * g0.x;  cor[1][si] -= alpha * g0.y;
        cor[2][si] -= alpha * g1.x;  cor[3][si] -= alpha * g1.y;
        cor[4][si] -= alpha * g2.x;  cor[5][si] -= alpha * g2.y;
        cor[6][si] -= alpha * g3.x;  cor[7][si] -= alpha * g3.y;
      }
    }
  }

  double s2 = 0.0;
#pragma unroll
  for (int r = 0; r < 4; ++r) {
    int c = (tid >> 5) + r * 16;
    int s = tid & 31;
    double v = s_al[0][s] * Dt[(size_t)c * NATOM + s_sel[0][s]];
#pragma unroll
    for (int tt = 1; tt < SPAR; ++tt)
      v += s_al[tt][s] * Dt[(size_t)c * NATOM + s_sel[tt][s]];
    float zv = (float)v;
    z_dl[((size_t)s * MDIM + c) * 1024 + l] = zv;
    double diff = (double)zv - xs[c][s];
    s2 += diff * diff;
  }
#pragma unroll
  for (int o = 32; o > 0; o >>= 1) s2 += __shfl_down(s2, o);
  if (lane == 0) s_red[w] = s2;
  __syncthreads();
  if (tid == 0) {
    double tsum = 0.0;
#pragma unroll
    for (int w2 = 0; w2 < 8; ++w2) tsum += s_red[w2];
    partial[bid] = tsum;
  }
  {
    float vals[32];
#pragma unroll
    for (int s = 0; s < 32; ++s) {
      float v = 0.0f;
#pragma unroll
      for (int tt = 0; tt < SPAR; ++tt)
        v = (s_sel[tt][s] == tid) ? (float)s_al[tt][s] : v;
      vals[s] = v;
    }
    float* cp = coeff + (size_t)tid * NSIG + (size_t)l * 32;
#pragma unroll
    for (int p = 0; p < 8; ++p) {
      float4 q = make_float4(vals[p*4+0], vals[p*4+1], vals[p*4+2], vals[p*4+3]);
      *(float4*)(cp + p * 4) = q;
    }
  }
}

// ---------------- finalize loss ---------------------------------------------
__global__ __launch_bounds__(64) void finalize_kernel(const double* __restrict__ partial,
                                                      float* __restrict__ loss_out) {
  double s = 0.0;
  for (int i = threadIdx.x; i < 1024; i += 64) s += partial[i];
#pragma unroll
  for (int o = 32; o > 0; o >>= 1) s += __shfl_down(s, o);
  if (threadIdx.x == 0) loss_out[0] = (float)(1.25 * s / 2097152.0);
}

extern "C" void kernel_launch(void* const* d_in, const int* in_sizes, int n_in,
                              void* d_out, int out_size, void* d_ws, size_t ws_size,
                              hipStream_t stream) {
  const float* z_e = (const float*)d_in[0];
  const float* D   = (const float*)d_in[1];

  float* out      = (float*)d_out;
  float* z_dl     = out;                       // 2097152 elems
  float* loss_out = out + 2097152;             // 1 elem
  float* coeff    = out + 2097153;             // 512*32768 elems

  char*   ws      = (char*)d_ws;
  double* partial = (double*)ws;                                       // 8 KiB
  double* Dt      = (double*)(ws + 8192);                              // 256 KiB
  double* nrm2    = (double*)(ws + 8192 + 262144);                     // 4 KiB
  double* G       = (double*)(ws + 8192 + 262144 + 4096);              // 2 MiB
  float*  xw      = (float*)(ws + 8192 + 262144 + 4096 + 2097152);     // 8 MiB
  const size_t need = 8192 + 262144 + 4096 + 2097152 + (size_t)NSIG * MDIM * 4;

  prep_kernel<<<1, 512, 0, stream>>>(D, Dt, nrm2);
  gram_kernel<<<NATOM, NATOM, 0, stream>>>(Dt, G);
  if (ws_size >= need) {
    repack_kernel<<<1024, 512, 0, stream>>>(z_e, xw);
    omp6_kernel<<<1024, 256, 0, stream>>>(xw, Dt, nrm2, G, z_dl, coeff, partial);
  } else {
    omp5_kernel<<<1024, 512, 0, stream>>>(z_e, Dt, nrm2, G, z_dl, coeff, partial);
  }
  finalize_kernel<<<1, 64, 0, stream>>>(partial, loss_out);
}